// Round 7
// baseline (651.308 us; speedup 1.0000x reference)
//
#include <hip/hip_runtime.h>
#include <cstdio>
#include <cstdint>

#define NREL 16
#define NBASE 8
// bin = (dst>>4)*16 + e_type. bucket = 16 consecutive dst nodes.
// Record packing: src[16:0] | dlow[20:17]   (N <= 2^17; r implicit in bin)

typedef _Float16 half8 __attribute__((ext_vector_type(8)));
typedef _Float16 half4v __attribute__((ext_vector_type(4)));
typedef float floatx4 __attribute__((ext_vector_type(4)));

// ---------------------------------------------------------------------------
// k_fused1: three independent jobs, selected by block range:
//   [0, nb_pre)            node_pre: hA1/hA2 (fp16) = h@A_w[0:32]/[32:64],
//                                    curr (f32) = h@slw, h16 = fp16(h)
//   [nb_pre, +nb_hist)     hist: deg[dst]++ and bincnt[(dst>>4)*16+et]++
//   [nb_pre+nb_hist, +64)  prep: relwB16 (B-frag layout), relA16, BwB16
// ---------------------------------------------------------------------------
__global__ __launch_bounds__(256) void k_fused1(
        const float* __restrict__ h, const float* __restrict__ A_w,
        const float* __restrict__ slw,
        const float* __restrict__ weight, const float* __restrict__ w_comp,
        const float* __restrict__ attn_emb, const float* __restrict__ A_b,
        const float* __restrict__ B_w,
        const int* __restrict__ dst, const int* __restrict__ et,
        _Float16* __restrict__ hA116, _Float16* __restrict__ hA216,
        float* __restrict__ curr, _Float16* __restrict__ h16,
        _Float16* __restrict__ relwB16, _Float16* __restrict__ relA16,
        _Float16* __restrict__ BwB16,
        int* __restrict__ deg, int* __restrict__ bincnt,
        int N, int E, int nb_pre, int nb_hist) {
    __shared__ __align__(16) float Wall[32 * 128];   // [i][c]: c<32 A1, <64 A2, <96 slw
    __shared__ float hbuf[8 * 33];
    int bx = blockIdx.x;
    int t = threadIdx.x;
    if (bx < nb_pre) {
        // ---- node_pre ----
        #pragma unroll
        for (int k = 0; k < 16; ++k) {
            int idx = t + 256 * k;
            int i = idx >> 7, c = idx & 127;
            float v = 0.f;
            if (c < 32)       v = A_w[i * 32 + c];
            else if (c < 64)  v = A_w[(32 + i) * 32 + (c - 32)];
            else if (c < 96)  v = slw[i * 32 + (c - 64)];
            Wall[idx] = v;
        }
        int n0 = bx * 8;
        int row = t >> 5, col = t & 31;
        {
            int n = n0 + row;
            hbuf[row * 33 + col] = (n < N) ? h[n * 32 + col] : 0.f;
        }
        // h16 copy (same thread wrote hbuf slot; no sync needed)
        {
            int n = n0 + row;
            if (n < N) h16[n * 32 + col] = (_Float16)hbuf[row * 33 + col];
        }
        __syncthreads();
        int nl = t >> 5;
        int c4 = (t & 31) * 4;
        float4 acc = {0.f, 0.f, 0.f, 0.f};
        #pragma unroll 8
        for (int i = 0; i < 32; ++i) {
            float hv = hbuf[nl * 33 + i];
            float4 w = *(const float4*)&Wall[i * 128 + c4];
            acc.x += hv * w.x; acc.y += hv * w.y; acc.z += hv * w.z; acc.w += hv * w.w;
        }
        int n = n0 + nl;
        if (n < N) {
            if (c4 < 32) {
                half4v hv = {(_Float16)acc.x, (_Float16)acc.y, (_Float16)acc.z, (_Float16)acc.w};
                *(half4v*)&hA116[n * 32 + c4] = hv;
            } else if (c4 < 64) {
                half4v hv = {(_Float16)acc.x, (_Float16)acc.y, (_Float16)acc.z, (_Float16)acc.w};
                *(half4v*)&hA216[n * 32 + (c4 - 32)] = hv;
            } else if (c4 < 96) {
                *(float4*)&curr[n * 32 + (c4 - 64)] = acc;
            }
        }
    } else if (bx < nb_pre + nb_hist) {
        // ---- hist: per-node degree + per-(bucket,rel) bin count ----
        int e = (bx - nb_pre) * 256 + t;
        if (e < E) {
            int d = dst[e];
            atomicAdd(&deg[d], 1);
            atomicAdd(&bincnt[(d >> 4) * 16 + et[e]], 1);
        }
    } else {
        // ---- prep ----
        int pidx = (bx - nb_pre - nb_hist) * 256 + t;    // 0..16383
        // relwB16: B-frag layout. pidx = r*1024 + nb*512 + l*8 + j
        int r = pidx >> 10, rem = pidx & 1023;
        int nb = rem >> 9, lj = rem & 511;
        int l = lj >> 3, j = lj & 7;
        int i = ((l >> 4) << 3) + j;          // k index
        int o = nb * 16 + (l & 15);           // n index
        float acc = 0.f;
        #pragma unroll
        for (int b = 0; b < NBASE; ++b)
            acc += w_comp[r * NBASE + b] * weight[b * 1024 + i * 32 + o];
        relwB16[pidx] = (_Float16)acc;
        if (pidx < 512) {
            // relA16 row-major [r][32]: includes A_b
            int rr = pidx >> 5, oo = pidx & 31;
            float a = A_b[oo];
            #pragma unroll 8
            for (int ii = 0; ii < 32; ++ii)
                a += attn_emb[rr * 32 + ii] * A_w[(64 + ii) * 32 + oo];
            relA16[pidx] = (_Float16)a;
        } else if (pidx < 1024) {
            // BwB16: broadcast-column B-frag of B_w
            int idx3 = pidx - 512;
            int ll = idx3 >> 3, jj = idx3 & 7;
            int kk = ((ll >> 4) << 3) + jj;
            BwB16[idx3] = (_Float16)B_w[kk];
        }
    }
}

// ---------------------------------------------------------------------------
// k_binscan1: two jobs by block range (1024 threads):
//   [0, nblk2)           per-block excl scan of pad16(bincnt) -> binpart + bsum
//   [nblk2, +nblkS)      scale_s += sum log(deg+1)
// ---------------------------------------------------------------------------
__global__ __launch_bounds__(1024) void k_binscan1(
        const int* __restrict__ bincnt, int* __restrict__ binpart,
        int* __restrict__ bsum, const int* __restrict__ deg,
        float* __restrict__ scale_s, int nbins, int N, int nblk2) {
    __shared__ int sd[1024];
    __shared__ float sf[1024];
    int t = threadIdx.x;
    int bx = blockIdx.x;
    if (bx < nblk2) {
        int gid = bx * 1024 + t;
        int c = (gid < nbins) ? bincnt[gid] : 0;
        int v = (c + 15) & ~15;                    // padded size
        sd[t] = v;
        __syncthreads();
        for (int off = 1; off < 1024; off <<= 1) {
            int x = (t >= off) ? sd[t - off] : 0;
            __syncthreads();
            sd[t] += x;
            __syncthreads();
        }
        if (gid < nbins) binpart[gid] = sd[t] - v;
        if (t == 1023) bsum[bx] = sd[1023];
    } else {
        int n = (bx - nblk2) * 1024 + t;
        sf[t] = (n < N) ? logf((float)deg[n] + 1.f) : 0.f;
        __syncthreads();
        for (int s2 = 512; s2 > 0; s2 >>= 1) {
            if (t < s2) sf[t] += sf[t + s2];
            __syncthreads();
        }
        if (t == 0) atomicAdd(scale_s, sf[0]);
    }
}

// ---------------------------------------------------------------------------
// k_binscan2: single block exclusive-scans bsum in place (chunked).
// ---------------------------------------------------------------------------
__global__ __launch_bounds__(1024) void k_binscan2(int* __restrict__ bsum, int nblk) {
    __shared__ int sd[1024];
    __shared__ int carry;
    int t = threadIdx.x;
    if (t == 0) carry = 0;
    __syncthreads();
    for (int base = 0; base < nblk; base += 1024) {
        int v = (base + t < nblk) ? bsum[base + t] : 0;
        sd[t] = v;
        __syncthreads();
        for (int off = 1; off < 1024; off <<= 1) {
            int x = (t >= off) ? sd[t - off] : 0;
            __syncthreads();
            sd[t] += x;
            __syncthreads();
        }
        int c = carry;
        if (base + t < nblk) bsum[base + t] = sd[t] - v + c;
        int tot = sd[1023];
        __syncthreads();
        if (t == 0) carry = c + tot;
        __syncthreads();
    }
}

// ---------------------------------------------------------------------------
// k_scatter: append edges into their (bucket,rel) bin's 64B-aligned region.
// Bin start = binpart[bin] + bsum[bin>>10] (padded-prefix reconstruction).
// ---------------------------------------------------------------------------
__global__ void k_scatter(const int* __restrict__ src, const int* __restrict__ dst,
        const int* __restrict__ et,
        const int* __restrict__ binpart, const int* __restrict__ bsum,
        int* __restrict__ bcur, int* __restrict__ packed, int E) {
    int e = blockIdx.x * 256 + threadIdx.x;
    if (e >= E) return;
    int d = dst[e];
    int bin = (d >> 4) * 16 + et[e];
    int pos = binpart[bin] + bsum[bin >> 10] + atomicAdd(&bcur[bin], 1);
    packed[pos] = src[e] | ((d & 15) << 17);
}

// ---------------------------------------------------------------------------
// k_node_agg: one block per 16-node bucket; wave w handles rels w,w+4,w+8,w+12.
// Per 16-record group (shared r): 3x mfma_f32_16x16x32_f16:
//   P   = relu(hA1[s]+hA2[d]+relA[r]) @ Bw_bcast   (attention logits, D rows=records)
//   MSG = H16[s rows] @ rel_w[r]                    (two n-halves)
// a = sigmoid(P+bb); lds_agg[dl][o] += a*MSG via LDS atomics (layout-aligned).
// Pad slots masked by zeroing the h A-frag rows. Fused epilogue.
// ---------------------------------------------------------------------------
__global__ __launch_bounds__(256) void k_node_agg(
        const _Float16* __restrict__ h16, const _Float16* __restrict__ hA116,
        const _Float16* __restrict__ hA216, const _Float16* __restrict__ relA16,
        const _Float16* __restrict__ relwB16, const _Float16* __restrict__ BwB16,
        const float* __restrict__ B_b,
        const float* __restrict__ curr, const float* __restrict__ bias,
        const int* __restrict__ deg, const int* __restrict__ bincnt,
        const int* __restrict__ binpart, const int* __restrict__ bsum,
        const int* __restrict__ packed, const float* __restrict__ scale_s,
        float* __restrict__ out, int N) {
    __shared__ float lds_agg[16 * 32];
    int t = threadIdx.x;
    int bk = blockIdx.x;
    int n0 = bk * 16;
    lds_agg[t] = 0.f;
    lds_agg[t + 256] = 0.f;
    __syncthreads();

    int wave = t >> 6, l = t & 63;
    int m = l & 15;                 // record slot / D col
    int g4 = l >> 4;                // k-group
    half8 bwf = *(const half8*)(BwB16 + l * 8);
    float bb = B_b[0];
    const half8 HZ = {(_Float16)0, (_Float16)0, (_Float16)0, (_Float16)0,
                      (_Float16)0, (_Float16)0, (_Float16)0, (_Float16)0};

    for (int r = wave; r < NREL; r += 4) {
        int bin = bk * 16 + r;
        int cnt = bincnt[bin];
        if (cnt == 0) continue;
        int base = binpart[bin] + bsum[bin >> 10];
        half8 bf0 = *(const half8*)(relwB16 + ((size_t)bin << 10) - ((size_t)(bk * 16 + r) << 10) + (size_t)r * 1024 + l * 8);
        // (bin<<10 cancels; keep it simple:)
        bf0 = *(const half8*)(relwB16 + (size_t)r * 1024 + l * 8);
        half8 bf1 = *(const half8*)(relwB16 + (size_t)r * 1024 + 512 + l * 8);
        half8 ra  = *(const half8*)(relA16 + r * 32 + g4 * 8);
        for (int g0 = 0; g0 < cnt; g0 += 16) {
            int rem = cnt - g0;
            bool val = (m < rem);
            int pk = val ? packed[base + g0 + m] : 0;
            int s  = pk & 0x1FFFF;
            int dl = (pk >> 17) & 15;
            // msg A-frag (zeroed for pad rows)
            half8 ha = *(const half8*)(h16 + (size_t)s * 32 + g4 * 8);
            if (!val) ha = HZ;
            // attention z in packed fp16, already in A-frag layout
            half8 a1 = *(const half8*)(hA116 + (size_t)s * 32 + g4 * 8);
            half8 a2 = *(const half8*)(hA216 + (size_t)(n0 + dl) * 32 + g4 * 8);
            half8 z = a1 + a2 + ra;
            half8 zr;
            #pragma unroll
            for (int j = 0; j < 8; ++j)
                zr[j] = (z[j] > (_Float16)0) ? z[j] : (_Float16)0;
            floatx4 pacc = {0.f, 0.f, 0.f, 0.f};
            floatx4 m0   = {0.f, 0.f, 0.f, 0.f};
            floatx4 m1   = {0.f, 0.f, 0.f, 0.f};
            pacc = __builtin_amdgcn_mfma_f32_16x16x32_f16(zr, bwf, pacc, 0, 0, 0);
            m0   = __builtin_amdgcn_mfma_f32_16x16x32_f16(ha, bf0, m0, 0, 0, 0);
            m1   = __builtin_amdgcn_mfma_f32_16x16x32_f16(ha, bf1, m1, 0, 0, 0);
            #pragma unroll
            for (int q = 0; q < 4; ++q) {
                int rr = g4 * 4 + q;                     // D row = record index
                int pkq = __shfl(pk, rr, 64);            // lane rr holds record rr
                int dlq = (pkq >> 17) & 15;
                float a = 1.f / (1.f + __expf(-(pacc[q] + bb)));
                atomicAdd(&lds_agg[dlq * 32 + m], a * m0[q]);
                atomicAdd(&lds_agg[dlq * 32 + 16 + m], a * m1[q]);
            }
        }
    }
    __syncthreads();

    float smean = scale_s[0] / (float)N;
    #pragma unroll
    for (int k2 = 0; k2 < 2; ++k2) {
        int idx = t + 256 * k2;                          // 0..511
        int row = idx >> 5, oo = idx & 31;
        int n = n0 + row;
        if (n < N) {
            float dv = (float)deg[n];
            float sc = logf(dv + 1.f);
            float v = curr[n * 32 + oo]
                    + (sc / smean) * lds_agg[idx] / fmaxf(dv, 1.f)
                    + bias[oo];
            out[n * 32 + oo] = fmaxf(v, 0.f);
        }
    }
}

extern "C" void kernel_launch(void* const* d_in, const int* in_sizes, int n_in,
                              void* d_out, int out_size, void* d_ws, size_t ws_size,
                              hipStream_t stream) {
    const float* h        = (const float*)d_in[0];
    const float* weight   = (const float*)d_in[1];
    const float* w_comp   = (const float*)d_in[2];
    const float* slw      = (const float*)d_in[3];
    const float* bias     = (const float*)d_in[4];
    const float* attn_emb = (const float*)d_in[5];
    const float* A_w      = (const float*)d_in[6];
    const float* A_b      = (const float*)d_in[7];
    const float* B_w      = (const float*)d_in[8];
    const float* B_b      = (const float*)d_in[9];
    const int*   src      = (const int*)d_in[10];
    const int*   dst      = (const int*)d_in[11];
    const int*   et       = (const int*)d_in[12];
    float*       out      = (float*)d_out;

    int N = in_sizes[0] / 32;
    int E = in_sizes[10];
    int nbuck = (N + 15) >> 4;
    int nbins = nbuck * 16;
    int nblk2 = (nbins + 1023) / 1024;
    int nblkS = (N + 1023) / 1024;

    char* ws = (char*)d_ws;
    size_t off = 0;
    auto alloc = [&](size_t nbytes) {
        char* p = ws + off;
        off += (nbytes + 63) & ~((size_t)63);
        return p;
    };
    int*      deg     = (int*)     alloc((size_t)N * 4);
    int*      bincnt  = (int*)     alloc((size_t)nbins * 4);
    int*      bcur    = (int*)     alloc((size_t)nbins * 4);
    float*    scale_s = (float*)   alloc(4);
    size_t zero_bytes = off;                       // deg + bincnt + bcur + scale_s
    int*      binpart = (int*)     alloc((size_t)nbins * 4);
    int*      bsum    = (int*)     alloc((size_t)(nblk2 + 1) * 4);
    _Float16* relwB16 = (_Float16*)alloc((size_t)NREL * 1024 * 2);
    _Float16* relA16  = (_Float16*)alloc((size_t)NREL * 32 * 2);
    _Float16* BwB16   = (_Float16*)alloc((size_t)512 * 2);
    _Float16* hA116   = (_Float16*)alloc((size_t)N * 32 * 2);
    _Float16* hA216   = (_Float16*)alloc((size_t)N * 32 * 2);
    float*    curr    = (float*)   alloc((size_t)N * 32 * 4);
    _Float16* h16     = (_Float16*)alloc((size_t)N * 32 * 2);
    int*      packed  = (int*)     alloc(((size_t)E + 16 * (size_t)nbins) * 4);
    size_t need = off;

    if (ws_size < need) {
        fprintf(stderr, "kernel_launch: ws too small (%zu < %zu bytes) — no work launched\n",
                ws_size, need);
        return;
    }

    (void)hipMemsetAsync(d_ws, 0, zero_bytes, stream);

    int nb_pre  = (N + 7) / 8;
    int nb_hist = (E + 255) / 256;
    int nb_prep = 64;
    k_fused1<<<nb_pre + nb_hist + nb_prep, 256, 0, stream>>>(
        h, A_w, slw, weight, w_comp, attn_emb, A_b, B_w, dst, et,
        hA116, hA216, curr, h16, relwB16, relA16, BwB16,
        deg, bincnt, N, E, nb_pre, nb_hist);

    k_binscan1<<<nblk2 + nblkS, 1024, 0, stream>>>(
        bincnt, binpart, bsum, deg, scale_s, nbins, N, nblk2);
    k_binscan2<<<1, 1024, 0, stream>>>(bsum, nblk2);

    k_scatter<<<(E + 255) / 256, 256, 0, stream>>>(
        src, dst, et, binpart, bsum, bcur, packed, E);

    k_node_agg<<<nbuck, 256, 0, stream>>>(
        h16, hA116, hA216, relA16, relwB16, BwB16, B_b, curr, bias,
        deg, bincnt, binpart, bsum, packed, scale_s, out, N);
}

// Round 8
// 615.029 us; speedup vs baseline: 1.0590x; 1.0590x over previous
//
#include <hip/hip_runtime.h>
#include <hip/hip_fp16.h>
#include <cstdio>
#include <cstdint>

#define NREL 16
#define NBASE 8
// Coarse bin = 128 consecutive dst nodes (dst>>7).
// Record packing: src[16:0] | et[20:17] | dlow[27:21]   (N <= 2^17)

// ---------------------------------------------------------------------------
// DPP-based partial-row add (VALU pipe, not LDS): x += dpp_shifted(x).
// ---------------------------------------------------------------------------
template <int CTRL>
__device__ __forceinline__ float dpp_add_f(float x) {
    int xi = __builtin_bit_cast(int, x);
    int yi = __builtin_amdgcn_update_dpp(0, xi, CTRL, 0xF, 0xF, true);
    return x + __builtin_bit_cast(float, yi);
}

// ---------------------------------------------------------------------------
// k_fused1: three independent jobs, selected by block range:
//   [0, nb_pre)            node_pre: hA1(fp16)=h@A_w[0:32], hA2=h@A_w[32:64],
//                                    curr=h@slw            (8 nodes/block)
//   [nb_pre, +nb_hist)     hist:     deg[dst[e]] += 1
//   [nb_pre+nb_hist, +64)  prep:     rel_w = w_comp@weight; relA
// ---------------------------------------------------------------------------
__global__ __launch_bounds__(256) void k_fused1(
        const float* __restrict__ h, const float* __restrict__ A_w,
        const float* __restrict__ slw,
        const float* __restrict__ weight, const float* __restrict__ w_comp,
        const float* __restrict__ attn_emb, const float* __restrict__ A_b,
        const int* __restrict__ dst,
        __half* __restrict__ hA1, float* __restrict__ hA2, float* __restrict__ curr,
        float* __restrict__ rel_w, float* __restrict__ relA, int* __restrict__ deg,
        int N, int E, int nb_pre, int nb_hist) {
    __shared__ __align__(16) float Wall[32 * 128];   // [i][c]: c<32 A1, <64 A2, <96 slw
    __shared__ float hbuf[8 * 33];
    int bx = blockIdx.x;
    int t = threadIdx.x;
    if (bx < nb_pre) {
        // ---- node_pre ----
        #pragma unroll
        for (int k = 0; k < 16; ++k) {
            int idx = t + 256 * k;
            int i = idx >> 7, c = idx & 127;
            float v = 0.f;
            if (c < 32)       v = A_w[i * 32 + c];
            else if (c < 64)  v = A_w[(32 + i) * 32 + (c - 32)];
            else if (c < 96)  v = slw[i * 32 + (c - 64)];
            Wall[idx] = v;
        }
        int n0 = bx * 8;
        {
            int row = t >> 5, col = t & 31;
            int n = n0 + row;
            hbuf[row * 33 + col] = (n < N) ? h[n * 32 + col] : 0.f;
        }
        __syncthreads();
        int nl = t >> 5;
        int c4 = (t & 31) * 4;
        float4 acc = {0.f, 0.f, 0.f, 0.f};
        #pragma unroll 8
        for (int i = 0; i < 32; ++i) {
            float hv = hbuf[nl * 33 + i];
            float4 w = *(const float4*)&Wall[i * 128 + c4];
            acc.x += hv * w.x; acc.y += hv * w.y; acc.z += hv * w.z; acc.w += hv * w.w;
        }
        int n = n0 + nl;
        if (n < N) {
            if (c4 < 32) {
                *(__half2*)&hA1[n * 32 + c4]     = __floats2half2_rn(acc.x, acc.y);
                *(__half2*)&hA1[n * 32 + c4 + 2] = __floats2half2_rn(acc.z, acc.w);
            } else if (c4 < 64) {
                *(float4*)&hA2[n * 32 + (c4 - 32)] = acc;
            } else if (c4 < 96) {
                *(float4*)&curr[n * 32 + (c4 - 64)] = acc;
            }
        }
    } else if (bx < nb_pre + nb_hist) {
        // ---- hist ----
        int e = (bx - nb_pre) * 256 + t;
        if (e < E) atomicAdd(&deg[dst[e]], 1);
    } else {
        // ---- prep ----
        int idx = (bx - nb_pre - nb_hist) * 256 + t;     // 0..16383
        int r = idx >> 10, io = idx & 1023;
        float acc = 0.f;
        #pragma unroll
        for (int b = 0; b < NBASE; ++b)
            acc += w_comp[r * NBASE + b] * weight[b * 1024 + io];
        rel_w[idx] = acc;
        if (idx < NREL * 32) {
            int rr = idx >> 5, o = idx & 31;
            float a = A_b[o];
            #pragma unroll 8
            for (int i = 0; i < 32; ++i)
                a += attn_emb[rr * 32 + i] * A_w[(64 + i) * 32 + o];
            relA[idx] = a;
        }
    }
}

// ---------------------------------------------------------------------------
// k_scan1: per-block exclusive scan of deg -> rowptr_p (block-local) + bsum
// (raw block totals). Also sum of log(deg+1) into scale_s.
// rowptr(n) = rowptr_p[n] + bsum[n>>8] after k_scan2.
// ---------------------------------------------------------------------------
__global__ __launch_bounds__(256) void k_scan1(const int* __restrict__ deg,
        int* __restrict__ rowptr_p, int* __restrict__ bsum,
        float* __restrict__ scale_s, int N) {
    __shared__ int sd[256];
    __shared__ float sf[256];
    int t = threadIdx.x;
    int gid = blockIdx.x * 256 + t;
    int v = (gid < N) ? deg[gid] : 0;
    sd[t] = v;
    sf[t] = (gid < N) ? logf((float)v + 1.0f) : 0.f;
    __syncthreads();
    for (int off = 1; off < 256; off <<= 1) {
        int x = (t >= off) ? sd[t - off] : 0;
        __syncthreads();
        sd[t] += x;
        __syncthreads();
    }
    if (gid < N) rowptr_p[gid] = sd[t] - v;
    if (t == 255) bsum[blockIdx.x] = sd[255];
    for (int s2 = 128; s2 > 0; s2 >>= 1) {
        if (t < s2) sf[t] += sf[t + s2];
        __syncthreads();
    }
    if (t == 0) atomicAdd(scale_s, sf[0]);
}

// ---------------------------------------------------------------------------
// k_scan2: single block exclusive-scans bsum in place (chunked for any nblk).
// ---------------------------------------------------------------------------
__global__ __launch_bounds__(1024) void k_scan2(int* __restrict__ bsum, int nblk) {
    __shared__ int sd[1024];
    __shared__ int carry;
    int t = threadIdx.x;
    if (t == 0) carry = 0;
    __syncthreads();
    for (int base = 0; base < nblk; base += 1024) {
        int v = (base + t < nblk) ? bsum[base + t] : 0;
        sd[t] = v;
        __syncthreads();
        for (int off = 1; off < 1024; off <<= 1) {
            int x = (t >= off) ? sd[t - off] : 0;
            __syncthreads();
            sd[t] += x;
            __syncthreads();
        }
        int c = carry;
        if (base + t < nblk) bsum[base + t] = sd[t] - v + c;
        int tot = sd[1023];
        __syncthreads();
        if (t == 0) carry = c + tot;
        __syncthreads();
    }
}

// ---------------------------------------------------------------------------
// k_fused2: two independent jobs by block range:
//   [0, nb_hrel)         hrel16[n][r*32+o] = fp16( sum_i h[n][i]*rel_w[r][i][o] )
//   [nb_hrel, +nb_scat)  coarse scatter: edges into their 128-node dst bin's
//                        contiguous region (random 4B writes confined to ~8KB
//                        hot windows -> lines fill in L2, ~1x amplification).
// ---------------------------------------------------------------------------
__global__ __launch_bounds__(256) void k_fused2(
        const float* __restrict__ h, const float* __restrict__ rel_w,
        __half* __restrict__ hrel16,
        const int* __restrict__ src, const int* __restrict__ dst,
        const int* __restrict__ et,
        const int* __restrict__ rowptr_p, const int* __restrict__ bsum,
        int* __restrict__ ccur, int* __restrict__ tmp,
        int N, int E, int nb_hrel) {
    __shared__ float hbuf[32 * 33];
    int bx = blockIdx.x;
    int t = threadIdx.x;
    if (bx < nb_hrel) {
        // ---- hrel (fp16 out) ----
        int n0 = bx * 32;
        #pragma unroll
        for (int k = 0; k < 4; ++k) {
            int idx = t + 256 * k;
            int row = idx >> 5, col = idx & 31;
            int n = n0 + row;
            hbuf[row * 33 + col] = (n < N) ? h[n * 32 + col] : 0.f;
        }
        __syncthreads();
        int w = t >> 6;
        int lane = t & 63;
        const float4* Wg = (const float4*)rel_w;
        int base_f4 = (lane >> 3) * 256 + (lane & 7);
        float4 a0[8], a1[8];
        #pragma unroll
        for (int j = 0; j < 8; ++j) {
            a0[j] = make_float4(0.f, 0.f, 0.f, 0.f);
            a1[j] = make_float4(0.f, 0.f, 0.f, 0.f);
        }
        int brow = w * 8;
        #pragma unroll 4
        for (int i = 0; i < 32; ++i) {
            float4 w0 = Wg[base_f4 + i * 8];
            float4 w1 = Wg[base_f4 + i * 8 + 2048];
            #pragma unroll
            for (int j = 0; j < 8; ++j) {
                float hv = hbuf[(brow + j) * 33 + i];
                a0[j].x += hv * w0.x; a0[j].y += hv * w0.y; a0[j].z += hv * w0.z; a0[j].w += hv * w0.w;
                a1[j].x += hv * w1.x; a1[j].y += hv * w1.y; a1[j].z += hv * w1.z; a1[j].w += hv * w1.w;
            }
        }
        #pragma unroll
        for (int j = 0; j < 8; ++j) {
            int n = n0 + brow + j;
            if (n < N) {
                size_t b0 = (size_t)n * 512 + lane * 4;
                *(__half2*)&hrel16[b0]       = __floats2half2_rn(a0[j].x, a0[j].y);
                *(__half2*)&hrel16[b0 + 2]   = __floats2half2_rn(a0[j].z, a0[j].w);
                *(__half2*)&hrel16[b0 + 256] = __floats2half2_rn(a1[j].x, a1[j].y);
                *(__half2*)&hrel16[b0 + 258] = __floats2half2_rn(a1[j].z, a1[j].w);
            }
        }
    } else {
        // ---- coarse scatter ----
        int e = (bx - nb_hrel) * 256 + t;
        if (e < E) {
            int d = dst[e];
            int b = d >> 7;                            // coarse bin
            int nb0 = b << 7;
            int base = rowptr_p[nb0] + bsum[nb0 >> 8]; // rowptr(b*128)
            int pos = base + atomicAdd(&ccur[b], 1);
            tmp[pos] = src[e] | (et[e] << 17) | ((d & 127) << 21);
        }
    }
}

// ---------------------------------------------------------------------------
// k_sortbin: one block per 128-node coarse bin. Refines the coarse region to
// exact per-node CSR order using 128 LDS cursors. Reads coalesced; writes are
// a permutation within the same ~8KB region (stays hot in L2).
// ---------------------------------------------------------------------------
__global__ __launch_bounds__(256) void k_sortbin(
        const int* __restrict__ tmp, int* __restrict__ packed,
        const int* __restrict__ rowptr_p, const int* __restrict__ bsum,
        int N, int E) {
    __shared__ int cur[128];
    int t = threadIdx.x;
    int b = blockIdx.x;
    int n0 = b << 7;
    if (t < 128) cur[t] = 0;
    __syncthreads();
    int start = rowptr_p[n0] + bsum[n0 >> 8];
    int n1 = n0 + 128;
    int endR = (n1 < N) ? (rowptr_p[n1] + bsum[n1 >> 8]) : E;
    for (int i = start + t; i < endR; i += 256) {
        int rec = tmp[i];
        int dlow = (rec >> 21) & 127;
        int d = n0 + dlow;
        int pos = rowptr_p[d] + bsum[d >> 8] + atomicAdd(&cur[dlow], 1);
        packed[pos] = rec;
    }
}

// ---------------------------------------------------------------------------
// k_node_agg: one node per 64-lane wave, 2 edges per step (one per 32-half),
// 2 steps batched (4 edges' gathers in flight). CSR gather from fp16 tables,
// DPP attention reduce, register accumulate, fused epilogue.
// ---------------------------------------------------------------------------
__global__ __launch_bounds__(256) void k_node_agg(
        const __half* __restrict__ hrel16, const __half* __restrict__ hA1,
        const float* __restrict__ hA2, const float* __restrict__ relA,
        const float* __restrict__ B_w, const float* __restrict__ B_b,
        const float* __restrict__ curr, const float* __restrict__ bias,
        const int* __restrict__ rowptr_p, const int* __restrict__ bsum,
        const int* __restrict__ packed, const float* __restrict__ scale_s,
        float* __restrict__ out, int N, int E) {
    int t = threadIdx.x;
    int wave = t >> 6, t64 = t & 63;
    int half = t64 >> 5, o = t64 & 31;
    int n = blockIdx.x * 4 + wave;
    if (n >= N) return;
    int r0 = rowptr_p[n] + bsum[n >> 8];
    int r1 = (n + 1 < N) ? (rowptr_p[n + 1] + bsum[(n + 1) >> 8]) : E;
    float hA2n = hA2[n * 32 + o];
    float bwo = B_w[o];
    float bb  = B_b[0];
    float acc = 0.f;
    for (int c0 = r0; c0 < r1; c0 += 64) {
        int j = c0 + t64;
        int pk = (j < r1) ? packed[j] : 0;
        int m = r1 - c0; if (m > 64) m = 64;
        for (int k = 0; k < m; k += 4) {
            int idxA = k + half;                   // first record-pair
            int idxB = k + 2 + half;               // second record-pair
            int pkA = __shfl(pk, idxA, 64);
            int pkB = __shfl(pk, idxB, 64);
            int sA = pkA & 0x1FFFF, rA = (pkA >> 17) & 15;
            int sB = pkB & 0x1FFFF, rB = (pkB >> 17) & 15;
            // issue all four gathers before any math
            float msgA = __half2float(hrel16[(size_t)sA * 512 + (rA << 5) + o]);
            float a1A  = __half2float(hA1[(sA << 5) + o]);
            float msgB = __half2float(hrel16[(size_t)sB * 512 + (rB << 5) + o]);
            float a1B  = __half2float(hA1[(sB << 5) + o]);
            float zA = a1A + hA2n + relA[(rA << 5) + o];
            float zB = a1B + hA2n + relA[(rB << 5) + o];
            float pA = fmaxf(zA, 0.f) * bwo;
            float pB = fmaxf(zB, 0.f) * bwo;
            // two independent 32-lane DPP reduces (compiler interleaves)
            pA = dpp_add_f<0x111>(pA); pB = dpp_add_f<0x111>(pB);
            pA = dpp_add_f<0x112>(pA); pB = dpp_add_f<0x112>(pB);
            pA = dpp_add_f<0x114>(pA); pB = dpp_add_f<0x114>(pB);
            pA = dpp_add_f<0x118>(pA); pB = dpp_add_f<0x118>(pB);
            pA = dpp_add_f<0x142>(pA); pB = dpp_add_f<0x142>(pB);
            pA = __shfl(pA, 31, 32) + bb;
            pB = __shfl(pB, 31, 32) + bb;
            float aA = 1.f / (1.f + __expf(-pA));
            float aB = 1.f / (1.f + __expf(-pB));
            acc += (idxA < m) ? aA * msgA : 0.f;
            acc += (idxB < m) ? aB * msgB : 0.f;
        }
    }
    acc += __shfl_xor(acc, 32, 64);                // combine the two halves
    if (half == 0) {
        float deg = (float)(r1 - r0);
        float smean = scale_s[0] / (float)N;
        float scale = logf(deg + 1.0f);
        float v = curr[n * 32 + o] + (scale / smean) * acc / fmaxf(deg, 1.f) + bias[o];
        out[n * 32 + o] = fmaxf(v, 0.f);
    }
}

extern "C" void kernel_launch(void* const* d_in, const int* in_sizes, int n_in,
                              void* d_out, int out_size, void* d_ws, size_t ws_size,
                              hipStream_t stream) {
    const float* h        = (const float*)d_in[0];
    const float* weight   = (const float*)d_in[1];
    const float* w_comp   = (const float*)d_in[2];
    const float* slw      = (const float*)d_in[3];
    const float* bias     = (const float*)d_in[4];
    const float* attn_emb = (const float*)d_in[5];
    const float* A_w      = (const float*)d_in[6];
    const float* A_b      = (const float*)d_in[7];
    const float* B_w      = (const float*)d_in[8];
    const float* B_b      = (const float*)d_in[9];
    const int*   src      = (const int*)d_in[10];
    const int*   dst      = (const int*)d_in[11];
    const int*   et       = (const int*)d_in[12];
    float*       out      = (float*)d_out;

    int N = in_sizes[0] / 32;
    int E = in_sizes[10];
    int nblk = (N + 255) / 256;
    int NB = (N + 127) >> 7;                       // coarse bins

    char* ws = (char*)d_ws;
    size_t off = 0;
    auto alloc = [&](size_t nbytes) {
        char* p = ws + off;
        off += (nbytes + 63) & ~((size_t)63);
        return p;
    };
    int*    deg     = (int*)   alloc((size_t)N * 4);
    int*    ccur    = (int*)   alloc((size_t)NB * 4);
    float*  scale_s = (float*) alloc(4);
    size_t zero_bytes = off;                       // deg + ccur + scale_s
    int*    rowptr_p= (int*)   alloc((size_t)N * 4);
    int*    bsum    = (int*)   alloc((size_t)nblk * 4);
    float*  rel_w   = (float*) alloc((size_t)NREL * 1024 * 4);
    float*  relA    = (float*) alloc((size_t)NREL * 32 * 4);
    __half* hA1     = (__half*)alloc((size_t)N * 32 * 2);
    float*  hA2     = (float*) alloc((size_t)N * 32 * 4);
    float*  curr    = (float*) alloc((size_t)N * 32 * 4);
    int*    tmp     = (int*)   alloc((size_t)E * 4);
    int*    packed  = (int*)   alloc((size_t)E * 4);
    __half* hrel16  = (__half*)alloc((size_t)N * 512 * 2);
    size_t need = off;

    if (ws_size < need) {
        fprintf(stderr, "kernel_launch: ws too small (%zu < %zu bytes) — no work launched\n",
                ws_size, need);
        return;
    }

    (void)hipMemsetAsync(d_ws, 0, zero_bytes, stream);

    int nb_pre  = (N + 7) / 8;
    int nb_hist = (E + 255) / 256;
    int nb_prep = 64;
    k_fused1<<<nb_pre + nb_hist + nb_prep, 256, 0, stream>>>(
        h, A_w, slw, weight, w_comp, attn_emb, A_b, dst,
        hA1, hA2, curr, rel_w, relA, deg, N, E, nb_pre, nb_hist);

    k_scan1<<<nblk, 256, 0, stream>>>(deg, rowptr_p, bsum, scale_s, N);
    k_scan2<<<1, 1024, 0, stream>>>(bsum, nblk);

    int nb_hrel = (N + 31) / 32;
    int nb_scat = (E + 255) / 256;
    k_fused2<<<nb_hrel + nb_scat, 256, 0, stream>>>(
        h, rel_w, hrel16, src, dst, et, rowptr_p, bsum, ccur, tmp,
        N, E, nb_hrel);

    k_sortbin<<<NB, 256, 0, stream>>>(tmp, packed, rowptr_p, bsum, N, E);

    k_node_agg<<<(N + 3) / 4, 256, 0, stream>>>(
        hrel16, hA1, hA2, relA, B_w, B_b, curr, bias,
        rowptr_p, bsum, packed, scale_s, out, N, E);
}

// Round 9
// 274.742 us; speedup vs baseline: 2.3706x; 2.2386x over previous
//
#include <hip/hip_runtime.h>
#include <hip/hip_fp16.h>
#include <cstdio>
#include <cstdint>

#define NREL 16
#define NBASE 8
#define NPB 512            // nodes per super-bin (bin = dst >> 9)
#define NPLACE 256         // histogram/place blocks
// Record packing: src[16:0] | et[20:17] | dlow[29:21]  (N <= 2^17)

// ---------------------------------------------------------------------------
// DPP-based partial-row add (VALU pipe, not LDS): x += dpp_shifted(x).
// ---------------------------------------------------------------------------
template <int CTRL>
__device__ __forceinline__ float dpp_add_f(float x) {
    int xi = __builtin_bit_cast(int, x);
    int yi = __builtin_amdgcn_update_dpp(0, xi, CTRL, 0xF, 0xF, true);
    return x + __builtin_bit_cast(float, yi);
}

// ---------------------------------------------------------------------------
// k_fused1: four independent jobs, selected by block range:
//   [0, nb_pre)                node_pre: hA1(fp16)=h@A_w[0:32], hA2=h@A_w[32:64],
//                                        curr=h@slw        (8 nodes/block)
//   [nb_pre, +nb_hist)         deg histogram (per-node, ~16 hits/counter: OK)
//   [nb_pre+nb_hist, +64)      prep: rel_w = w_comp@weight; relA
//   [nb_pre+nb_hist+64, +256)  hist2: per-(block,super-bin) LDS histogram
// ---------------------------------------------------------------------------
__global__ __launch_bounds__(256) void k_fused1(
        const float* __restrict__ h, const float* __restrict__ A_w,
        const float* __restrict__ slw,
        const float* __restrict__ weight, const float* __restrict__ w_comp,
        const float* __restrict__ attn_emb, const float* __restrict__ A_b,
        const int* __restrict__ dst,
        __half* __restrict__ hA1, float* __restrict__ hA2, float* __restrict__ curr,
        float* __restrict__ rel_w, float* __restrict__ relA, int* __restrict__ deg,
        int* __restrict__ histT,
        int N, int E, int nb_pre, int nb_hist) {
    __shared__ __align__(16) float Wall[32 * 128];   // [i][c]: c<32 A1, <64 A2, <96 slw
    __shared__ float hbuf[8 * 33];
    __shared__ int hist[256];
    int bx = blockIdx.x;
    int t = threadIdx.x;
    if (bx < nb_pre) {
        // ---- node_pre ----
        #pragma unroll
        for (int k = 0; k < 16; ++k) {
            int idx = t + 256 * k;
            int i = idx >> 7, c = idx & 127;
            float v = 0.f;
            if (c < 32)       v = A_w[i * 32 + c];
            else if (c < 64)  v = A_w[(32 + i) * 32 + (c - 32)];
            else if (c < 96)  v = slw[i * 32 + (c - 64)];
            Wall[idx] = v;
        }
        int n0 = bx * 8;
        {
            int row = t >> 5, col = t & 31;
            int n = n0 + row;
            hbuf[row * 33 + col] = (n < N) ? h[n * 32 + col] : 0.f;
        }
        __syncthreads();
        int nl = t >> 5;
        int c4 = (t & 31) * 4;
        float4 acc = {0.f, 0.f, 0.f, 0.f};
        #pragma unroll 8
        for (int i = 0; i < 32; ++i) {
            float hv = hbuf[nl * 33 + i];
            float4 w = *(const float4*)&Wall[i * 128 + c4];
            acc.x += hv * w.x; acc.y += hv * w.y; acc.z += hv * w.z; acc.w += hv * w.w;
        }
        int n = n0 + nl;
        if (n < N) {
            if (c4 < 32) {
                *(__half2*)&hA1[n * 32 + c4]     = __floats2half2_rn(acc.x, acc.y);
                *(__half2*)&hA1[n * 32 + c4 + 2] = __floats2half2_rn(acc.z, acc.w);
            } else if (c4 < 64) {
                *(float4*)&hA2[n * 32 + (c4 - 32)] = acc;
            } else if (c4 < 96) {
                *(float4*)&curr[n * 32 + (c4 - 64)] = acc;
            }
        }
    } else if (bx < nb_pre + nb_hist) {
        // ---- deg histogram ----
        int e = (bx - nb_pre) * 256 + t;
        if (e < E) atomicAdd(&deg[dst[e]], 1);
    } else if (bx < nb_pre + nb_hist + 64) {
        // ---- prep ----
        int idx = (bx - nb_pre - nb_hist) * 256 + t;     // 0..16383
        int r = idx >> 10, io = idx & 1023;
        float acc = 0.f;
        #pragma unroll
        for (int b = 0; b < NBASE; ++b)
            acc += w_comp[r * NBASE + b] * weight[b * 1024 + io];
        rel_w[idx] = acc;
        if (idx < NREL * 32) {
            int rr = idx >> 5, o = idx & 31;
            float a = A_b[o];
            #pragma unroll 8
            for (int i = 0; i < 32; ++i)
                a += attn_emb[rr * 32 + i] * A_w[(64 + i) * 32 + o];
            relA[idx] = a;
        }
    } else {
        // ---- hist2: per-(block,super-bin) counts ----
        int nsb = (N + NPB - 1) / NPB;
        hist[t] = 0;
        __syncthreads();
        int blk = bx - (nb_pre + nb_hist + 64);
        int bpb = (E + NPLACE - 1) / NPLACE;
        int e0 = blk * bpb;
        int e1 = e0 + bpb; if (e1 > E) e1 = E;
        for (int e = e0 + t; e < e1; e += 256)
            atomicAdd(&hist[dst[e] >> 9], 1);
        __syncthreads();
        if (t < nsb) histT[t * NPLACE + blk] = hist[t];
    }
}

// ---------------------------------------------------------------------------
// k_scan1: per-block exclusive scan of deg -> rowptr_p (block-local) + bsum.
// Also sum of log(deg+1) into scale_s. rowptr(n) = rowptr_p[n] + bsum[n>>8].
// ---------------------------------------------------------------------------
__global__ __launch_bounds__(256) void k_scan1(const int* __restrict__ deg,
        int* __restrict__ rowptr_p, int* __restrict__ bsum,
        float* __restrict__ scale_s, int N) {
    __shared__ int sd[256];
    __shared__ float sf[256];
    int t = threadIdx.x;
    int gid = blockIdx.x * 256 + t;
    int v = (gid < N) ? deg[gid] : 0;
    sd[t] = v;
    sf[t] = (gid < N) ? logf((float)v + 1.0f) : 0.f;
    __syncthreads();
    for (int off = 1; off < 256; off <<= 1) {
        int x = (t >= off) ? sd[t - off] : 0;
        __syncthreads();
        sd[t] += x;
        __syncthreads();
    }
    if (gid < N) rowptr_p[gid] = sd[t] - v;
    if (t == 255) bsum[blockIdx.x] = sd[255];
    for (int s2 = 128; s2 > 0; s2 >>= 1) {
        if (t < s2) sf[t] += sf[t + s2];
        __syncthreads();
    }
    if (t == 0) atomicAdd(scale_s, sf[0]);
}

// ---------------------------------------------------------------------------
// k_scan2: single block exclusive-scans bsum in place (chunked for any nblk).
// ---------------------------------------------------------------------------
__global__ __launch_bounds__(1024) void k_scan2(int* __restrict__ bsum, int nblk) {
    __shared__ int sd[1024];
    __shared__ int carry;
    int t = threadIdx.x;
    if (t == 0) carry = 0;
    __syncthreads();
    for (int base = 0; base < nblk; base += 1024) {
        int v = (base + t < nblk) ? bsum[base + t] : 0;
        sd[t] = v;
        __syncthreads();
        for (int off = 1; off < 1024; off <<= 1) {
            int x = (t >= off) ? sd[t - off] : 0;
            __syncthreads();
            sd[t] += x;
            __syncthreads();
        }
        int c = carry;
        if (base + t < nblk) bsum[base + t] = sd[t] - v + c;
        int tot = sd[1023];
        __syncthreads();
        if (t == 0) carry = c + tot;
        __syncthreads();
    }
}

// ---------------------------------------------------------------------------
// k_scanH: one block per super-bin. Exclusive scan over the bin's NPLACE
// block-counts + base rowptr(bin*NPB) -> histT holds ABSOLUTE offsets.
// ---------------------------------------------------------------------------
__global__ __launch_bounds__(NPLACE) void k_scanH(int* __restrict__ histT,
        const int* __restrict__ rowptr_p, const int* __restrict__ bsum) {
    __shared__ int sd[NPLACE];
    int bin = blockIdx.x, t = threadIdx.x;
    int v = histT[bin * NPLACE + t];
    sd[t] = v;
    __syncthreads();
    for (int off = 1; off < NPLACE; off <<= 1) {
        int x = (t >= off) ? sd[t - off] : 0;
        __syncthreads();
        sd[t] += x;
        __syncthreads();
    }
    int n0 = bin * NPB;
    int base = rowptr_p[n0] + bsum[n0 >> 8];
    histT[bin * NPLACE + t] = base + sd[t] - v;
}

// ---------------------------------------------------------------------------
// k_fused2: two independent jobs by block range:
//   [0, nb_hrel)          hrel16[n][r*32+o] = fp16( sum_i h[n][i]*rel_w[r][i][o] )
//   [nb_hrel, +NPLACE)    place: LDS cursors seeded with absolute offsets;
//                         each (block,bin) writes a contiguous ~128B run.
//                         Only LDS atomics — no global contention.
// ---------------------------------------------------------------------------
__global__ __launch_bounds__(256) void k_fused2(
        const float* __restrict__ h, const float* __restrict__ rel_w,
        __half* __restrict__ hrel16,
        const int* __restrict__ src, const int* __restrict__ dst,
        const int* __restrict__ et,
        const int* __restrict__ histT, int* __restrict__ tmp,
        int N, int E, int nb_hrel) {
    __shared__ float hbuf[32 * 33];
    __shared__ int cur[256];
    int bx = blockIdx.x;
    int t = threadIdx.x;
    if (bx < nb_hrel) {
        // ---- hrel (fp16 out) ----
        int n0 = bx * 32;
        #pragma unroll
        for (int k = 0; k < 4; ++k) {
            int idx = t + 256 * k;
            int row = idx >> 5, col = idx & 31;
            int n = n0 + row;
            hbuf[row * 33 + col] = (n < N) ? h[n * 32 + col] : 0.f;
        }
        __syncthreads();
        int w = t >> 6;
        int lane = t & 63;
        const float4* Wg = (const float4*)rel_w;
        int base_f4 = (lane >> 3) * 256 + (lane & 7);
        float4 a0[8], a1[8];
        #pragma unroll
        for (int j = 0; j < 8; ++j) {
            a0[j] = make_float4(0.f, 0.f, 0.f, 0.f);
            a1[j] = make_float4(0.f, 0.f, 0.f, 0.f);
        }
        int brow = w * 8;
        #pragma unroll 4
        for (int i = 0; i < 32; ++i) {
            float4 w0 = Wg[base_f4 + i * 8];
            float4 w1 = Wg[base_f4 + i * 8 + 2048];
            #pragma unroll
            for (int j = 0; j < 8; ++j) {
                float hv = hbuf[(brow + j) * 33 + i];
                a0[j].x += hv * w0.x; a0[j].y += hv * w0.y; a0[j].z += hv * w0.z; a0[j].w += hv * w0.w;
                a1[j].x += hv * w1.x; a1[j].y += hv * w1.y; a1[j].z += hv * w1.z; a1[j].w += hv * w1.w;
            }
        }
        #pragma unroll
        for (int j = 0; j < 8; ++j) {
            int n = n0 + brow + j;
            if (n < N) {
                size_t b0 = (size_t)n * 512 + lane * 4;
                *(__half2*)&hrel16[b0]       = __floats2half2_rn(a0[j].x, a0[j].y);
                *(__half2*)&hrel16[b0 + 2]   = __floats2half2_rn(a0[j].z, a0[j].w);
                *(__half2*)&hrel16[b0 + 256] = __floats2half2_rn(a1[j].x, a1[j].y);
                *(__half2*)&hrel16[b0 + 258] = __floats2half2_rn(a1[j].z, a1[j].w);
            }
        }
    } else {
        // ---- place ----
        int nsb = (N + NPB - 1) / NPB;
        int blk = bx - nb_hrel;
        if (t < nsb) cur[t] = histT[t * NPLACE + blk];
        __syncthreads();
        int bpb = (E + NPLACE - 1) / NPLACE;
        int e0 = blk * bpb;
        int e1 = e0 + bpb; if (e1 > E) e1 = E;
        for (int e = e0 + t; e < e1; e += 256) {
            int d = dst[e];
            int pos = atomicAdd(&cur[d >> 9], 1);    // absolute position
            tmp[pos] = src[e] | (et[e] << 17) | ((d & 511) << 21);
        }
    }
}

// ---------------------------------------------------------------------------
// k_sortbin: one block per super-bin. Refines the bin's region to exact
// per-node CSR order; LDS cursors seeded with absolute rowptr(n). Reads
// coalesced; writes random 4B within a single-block-hot ~32KB window.
// ---------------------------------------------------------------------------
__global__ __launch_bounds__(256) void k_sortbin(
        const int* __restrict__ tmp, int* __restrict__ packed,
        const int* __restrict__ rowptr_p, const int* __restrict__ bsum,
        int N, int E) {
    __shared__ int cur[NPB];
    int t = threadIdx.x;
    int bin = blockIdx.x;
    int n0 = bin * NPB;
    #pragma unroll
    for (int k = 0; k < NPB / 256; ++k) {
        int i = t + 256 * k;
        int n = n0 + i;
        cur[i] = (n < N) ? rowptr_p[n] + bsum[n >> 8] : 0;
    }
    __syncthreads();
    int start = rowptr_p[n0] + bsum[n0 >> 8];
    int n1 = n0 + NPB;
    int end = (n1 < N) ? (rowptr_p[n1] + bsum[n1 >> 8]) : E;
    for (int i = start + t; i < end; i += 256) {
        int rec = tmp[i];
        int dlow = (rec >> 21) & 511;
        int pos = atomicAdd(&cur[dlow], 1);
        packed[pos] = rec;
    }
}

// ---------------------------------------------------------------------------
// k_node_agg: one node per 64-lane wave, 2 edges per step (one per 32-half),
// 2 steps batched (4 edges' gathers in flight). CSR gather from fp16 tables,
// DPP attention reduce, register accumulate, fused epilogue.
// ---------------------------------------------------------------------------
__global__ __launch_bounds__(256) void k_node_agg(
        const __half* __restrict__ hrel16, const __half* __restrict__ hA1,
        const float* __restrict__ hA2, const float* __restrict__ relA,
        const float* __restrict__ B_w, const float* __restrict__ B_b,
        const float* __restrict__ curr, const float* __restrict__ bias,
        const int* __restrict__ rowptr_p, const int* __restrict__ bsum,
        const int* __restrict__ packed, const float* __restrict__ scale_s,
        float* __restrict__ out, int N, int E) {
    int t = threadIdx.x;
    int wave = t >> 6, t64 = t & 63;
    int half = t64 >> 5, o = t64 & 31;
    int n = blockIdx.x * 4 + wave;
    if (n >= N) return;
    int r0 = rowptr_p[n] + bsum[n >> 8];
    int r1 = (n + 1 < N) ? (rowptr_p[n + 1] + bsum[(n + 1) >> 8]) : E;
    float hA2n = hA2[n * 32 + o];
    float bwo = B_w[o];
    float bb  = B_b[0];
    float acc = 0.f;
    for (int c0 = r0; c0 < r1; c0 += 64) {
        int j = c0 + t64;
        int pk = (j < r1) ? packed[j] : 0;
        int m = r1 - c0; if (m > 64) m = 64;
        for (int k = 0; k < m; k += 4) {
            int idxA = k + half;
            int idxB = k + 2 + half;
            int pkA = __shfl(pk, idxA, 64);
            int pkB = __shfl(pk, idxB, 64);
            int sA = pkA & 0x1FFFF, rA = (pkA >> 17) & 15;
            int sB = pkB & 0x1FFFF, rB = (pkB >> 17) & 15;
            // issue all four gathers before any math
            float msgA = __half2float(hrel16[(size_t)sA * 512 + (rA << 5) + o]);
            float a1A  = __half2float(hA1[(sA << 5) + o]);
            float msgB = __half2float(hrel16[(size_t)sB * 512 + (rB << 5) + o]);
            float a1B  = __half2float(hA1[(sB << 5) + o]);
            float zA = a1A + hA2n + relA[(rA << 5) + o];
            float zB = a1B + hA2n + relA[(rB << 5) + o];
            float pA = fmaxf(zA, 0.f) * bwo;
            float pB = fmaxf(zB, 0.f) * bwo;
            pA = dpp_add_f<0x111>(pA); pB = dpp_add_f<0x111>(pB);
            pA = dpp_add_f<0x112>(pA); pB = dpp_add_f<0x112>(pB);
            pA = dpp_add_f<0x114>(pA); pB = dpp_add_f<0x114>(pB);
            pA = dpp_add_f<0x118>(pA); pB = dpp_add_f<0x118>(pB);
            pA = dpp_add_f<0x142>(pA); pB = dpp_add_f<0x142>(pB);
            pA = __shfl(pA, 31, 32) + bb;
            pB = __shfl(pB, 31, 32) + bb;
            float aA = 1.f / (1.f + __expf(-pA));
            float aB = 1.f / (1.f + __expf(-pB));
            acc += (idxA < m) ? aA * msgA : 0.f;
            acc += (idxB < m) ? aB * msgB : 0.f;
        }
    }
    acc += __shfl_xor(acc, 32, 64);
    if (half == 0) {
        float deg = (float)(r1 - r0);
        float smean = scale_s[0] / (float)N;
        float scale = logf(deg + 1.0f);
        float v = curr[n * 32 + o] + (scale / smean) * acc / fmaxf(deg, 1.f) + bias[o];
        out[n * 32 + o] = fmaxf(v, 0.f);
    }
}

extern "C" void kernel_launch(void* const* d_in, const int* in_sizes, int n_in,
                              void* d_out, int out_size, void* d_ws, size_t ws_size,
                              hipStream_t stream) {
    const float* h        = (const float*)d_in[0];
    const float* weight   = (const float*)d_in[1];
    const float* w_comp   = (const float*)d_in[2];
    const float* slw      = (const float*)d_in[3];
    const float* bias     = (const float*)d_in[4];
    const float* attn_emb = (const float*)d_in[5];
    const float* A_w      = (const float*)d_in[6];
    const float* A_b      = (const float*)d_in[7];
    const float* B_w      = (const float*)d_in[8];
    const float* B_b      = (const float*)d_in[9];
    const int*   src      = (const int*)d_in[10];
    const int*   dst      = (const int*)d_in[11];
    const int*   et       = (const int*)d_in[12];
    float*       out      = (float*)d_out;

    int N = in_sizes[0] / 32;
    int E = in_sizes[10];
    int nblk = (N + 255) / 256;
    int nsb = (N + NPB - 1) / NPB;                 // super-bins

    char* ws = (char*)d_ws;
    size_t off = 0;
    auto alloc = [&](size_t nbytes) {
        char* p = ws + off;
        off += (nbytes + 63) & ~((size_t)63);
        return p;
    };
    int*    deg     = (int*)   alloc((size_t)N * 4);
    float*  scale_s = (float*) alloc(4);
    size_t zero_bytes = off;                       // deg + scale_s (no cursors!)
    int*    rowptr_p= (int*)   alloc((size_t)N * 4);
    int*    bsum    = (int*)   alloc((size_t)nblk * 4);
    int*    histT   = (int*)   alloc((size_t)nsb * NPLACE * 4);
    float*  rel_w   = (float*) alloc((size_t)NREL * 1024 * 4);
    float*  relA    = (float*) alloc((size_t)NREL * 32 * 4);
    __half* hA1     = (__half*)alloc((size_t)N * 32 * 2);
    float*  hA2     = (float*) alloc((size_t)N * 32 * 4);
    float*  curr    = (float*) alloc((size_t)N * 32 * 4);
    int*    tmp     = (int*)   alloc((size_t)E * 4);
    int*    packed  = (int*)   alloc((size_t)E * 4);
    __half* hrel16  = (__half*)alloc((size_t)N * 512 * 2);
    size_t need = off;

    if (ws_size < need) {
        fprintf(stderr, "kernel_launch: ws too small (%zu < %zu bytes) — no work launched\n",
                ws_size, need);
        return;
    }

    (void)hipMemsetAsync(d_ws, 0, zero_bytes, stream);

    int nb_pre  = (N + 7) / 8;
    int nb_hist = (E + 255) / 256;
    k_fused1<<<nb_pre + nb_hist + 64 + NPLACE, 256, 0, stream>>>(
        h, A_w, slw, weight, w_comp, attn_emb, A_b, dst,
        hA1, hA2, curr, rel_w, relA, deg, histT, N, E, nb_pre, nb_hist);

    k_scan1<<<nblk, 256, 0, stream>>>(deg, rowptr_p, bsum, scale_s, N);
    k_scan2<<<1, 1024, 0, stream>>>(bsum, nblk);
    k_scanH<<<nsb, NPLACE, 0, stream>>>(histT, rowptr_p, bsum);

    int nb_hrel = (N + 31) / 32;
    k_fused2<<<nb_hrel + NPLACE, 256, 0, stream>>>(
        h, rel_w, hrel16, src, dst, et, histT, tmp, N, E, nb_hrel);

    k_sortbin<<<nsb, 256, 0, stream>>>(tmp, packed, rowptr_p, bsum, N, E);

    k_node_agg<<<(N + 3) / 4, 256, 0, stream>>>(
        hrel16, hA1, hA2, relA, B_w, B_b, curr, bias,
        rowptr_p, bsum, packed, scale_s, out, N, E);
}

// Round 10
// 199.352 us; speedup vs baseline: 3.2671x; 1.3782x over previous
//
#include <hip/hip_runtime.h>
#include <hip/hip_fp16.h>
#include <cstdio>
#include <cstdint>

#define NREL 16
#define NBASE 8
#define NPB 512            // nodes per super-bin (bin = dst >> 9)
#define NPLACE 256         // histogram/place blocks
// Record packing: src[16:0] | et[20:17] | dlow[29:21]  (N <= 2^17)

// ---------------------------------------------------------------------------
// DPP-based partial-row add (VALU pipe, not LDS): x += dpp_shifted(x).
// ---------------------------------------------------------------------------
template <int CTRL>
__device__ __forceinline__ float dpp_add_f(float x) {
    int xi = __builtin_bit_cast(int, x);
    int yi = __builtin_amdgcn_update_dpp(0, xi, CTRL, 0xF, 0xF, true);
    return x + __builtin_bit_cast(float, yi);
}

// ---------------------------------------------------------------------------
// k_fused1: three independent jobs, selected by block range:
//   [0, nb_pre)          node_pre (32 nodes/block): hA1(fp16)=h@A_w[0:32],
//                        hA2=h@A_w[32:64], curr=h@slw
//   [nb_pre, +64)        prep: rel_w = w_comp@weight; relA
//   [nb_pre+64, +NPLACE) hist2: per-(block,super-bin) LDS histogram of dst
// NO per-node global atomics anywhere.
// ---------------------------------------------------------------------------
__global__ __launch_bounds__(256) void k_fused1(
        const float* __restrict__ h, const float* __restrict__ A_w,
        const float* __restrict__ slw,
        const float* __restrict__ weight, const float* __restrict__ w_comp,
        const float* __restrict__ attn_emb, const float* __restrict__ A_b,
        const int* __restrict__ dst,
        __half* __restrict__ hA1, float* __restrict__ hA2, float* __restrict__ curr,
        float* __restrict__ rel_w, float* __restrict__ relA,
        int* __restrict__ histT,
        int N, int E, int nb_pre) {
    __shared__ __align__(16) float Wall[32 * 128];   // [i][c]: c<32 A1, <64 A2, <96 slw
    __shared__ float hbuf[32 * 33];
    __shared__ int hist[256];
    int bx = blockIdx.x;
    int t = threadIdx.x;
    if (bx < nb_pre) {
        // ---- node_pre: 32 nodes per block ----
        #pragma unroll
        for (int k = 0; k < 16; ++k) {
            int idx = t + 256 * k;
            int i = idx >> 7, c = idx & 127;
            float v = 0.f;
            if (c < 32)       v = A_w[i * 32 + c];
            else if (c < 64)  v = A_w[(32 + i) * 32 + (c - 32)];
            else if (c < 96)  v = slw[i * 32 + (c - 64)];
            Wall[idx] = v;
        }
        int n0 = bx * 32;
        #pragma unroll
        for (int k = 0; k < 4; ++k) {
            int idx = t + 256 * k;                   // 0..1023
            int row = idx >> 5, col = idx & 31;
            int n = n0 + row;
            hbuf[row * 33 + col] = (n < N) ? h[n * 32 + col] : 0.f;
        }
        __syncthreads();
        int nl = t >> 3;                             // node 0..31
        int tg = t & 7;                              // col-group 0..7 (12 cols each)
        float4 a0 = {0,0,0,0}, a1 = {0,0,0,0}, a2 = {0,0,0,0};
        #pragma unroll 8
        for (int i = 0; i < 32; ++i) {
            float hv = hbuf[nl * 33 + i];
            float4 w0 = *(const float4*)&Wall[i * 128 + tg * 12];
            float4 w1 = *(const float4*)&Wall[i * 128 + tg * 12 + 4];
            float4 w2 = *(const float4*)&Wall[i * 128 + tg * 12 + 8];
            a0.x += hv * w0.x; a0.y += hv * w0.y; a0.z += hv * w0.z; a0.w += hv * w0.w;
            a1.x += hv * w1.x; a1.y += hv * w1.y; a1.z += hv * w1.z; a1.w += hv * w1.w;
            a2.x += hv * w2.x; a2.y += hv * w2.y; a2.z += hv * w2.z; a2.w += hv * w2.w;
        }
        int n = n0 + nl;
        if (n < N) {
            float4 acc[3] = {a0, a1, a2};
            #pragma unroll
            for (int j = 0; j < 3; ++j) {
                int c = tg * 12 + j * 4;
                if (c < 32) {
                    *(__half2*)&hA1[n * 32 + c]     = __floats2half2_rn(acc[j].x, acc[j].y);
                    *(__half2*)&hA1[n * 32 + c + 2] = __floats2half2_rn(acc[j].z, acc[j].w);
                } else if (c < 64) {
                    *(float4*)&hA2[n * 32 + (c - 32)] = acc[j];
                } else {
                    *(float4*)&curr[n * 32 + (c - 64)] = acc[j];
                }
            }
        }
    } else if (bx < nb_pre + 64) {
        // ---- prep ----
        int idx = (bx - nb_pre) * 256 + t;           // 0..16383
        int r = idx >> 10, io = idx & 1023;
        float acc = 0.f;
        #pragma unroll
        for (int b = 0; b < NBASE; ++b)
            acc += w_comp[r * NBASE + b] * weight[b * 1024 + io];
        rel_w[idx] = acc;
        if (idx < NREL * 32) {
            int rr = idx >> 5, o = idx & 31;
            float a = A_b[o];
            #pragma unroll 8
            for (int i = 0; i < 32; ++i)
                a += attn_emb[rr * 32 + i] * A_w[(64 + i) * 32 + o];
            relA[idx] = a;
        }
    } else {
        // ---- hist2: per-(block,super-bin) counts ----
        int nsb = (N + NPB - 1) / NPB;
        hist[t] = 0;
        __syncthreads();
        int blk = bx - (nb_pre + 64);
        int bpb = (E + NPLACE - 1) / NPLACE;
        int e0 = blk * bpb;
        int e1 = e0 + bpb; if (e1 > E) e1 = E;
        for (int e = e0 + t; e < e1; e += 256)
            atomicAdd(&hist[dst[e] >> 9], 1);
        __syncthreads();
        if (t < nsb) histT[t * NPLACE + blk] = hist[t];
    }
}

// ---------------------------------------------------------------------------
// k_scanH: one block per super-bin. Exclusive scan over the bin's NPLACE
// block-counts (in place, bin-LOCAL); bin total -> binTot[bin].
// ---------------------------------------------------------------------------
__global__ __launch_bounds__(NPLACE) void k_scanH(int* __restrict__ histT,
        int* __restrict__ binTot) {
    __shared__ int sd[NPLACE];
    int bin = blockIdx.x, t = threadIdx.x;
    int v = histT[bin * NPLACE + t];
    sd[t] = v;
    __syncthreads();
    for (int off = 1; off < NPLACE; off <<= 1) {
        int x = (t >= off) ? sd[t - off] : 0;
        __syncthreads();
        sd[t] += x;
        __syncthreads();
    }
    histT[bin * NPLACE + t] = sd[t] - v;
    if (t == NPLACE - 1) binTot[bin] = sd[NPLACE - 1];
}

// ---------------------------------------------------------------------------
// k_scanB: single block exclusive-scans binTot in place (chunked);
// binTot[nsb] = total (= E).
// ---------------------------------------------------------------------------
__global__ __launch_bounds__(1024) void k_scanB(int* __restrict__ binTot, int nsb) {
    __shared__ int sd[1024];
    __shared__ int carry;
    int t = threadIdx.x;
    if (t == 0) carry = 0;
    __syncthreads();
    for (int base = 0; base < nsb; base += 1024) {
        int v = (base + t < nsb) ? binTot[base + t] : 0;
        sd[t] = v;
        __syncthreads();
        for (int off = 1; off < 1024; off <<= 1) {
            int x = (t >= off) ? sd[t - off] : 0;
            __syncthreads();
            sd[t] += x;
            __syncthreads();
        }
        int c = carry;
        if (base + t < nsb) binTot[base + t] = sd[t] - v + c;
        int tot = sd[1023];
        __syncthreads();
        if (t == 0) carry = c + tot;
        __syncthreads();
    }
    if (t == 0) binTot[nsb] = carry;
}

// ---------------------------------------------------------------------------
// k_fused2: two independent jobs by block range:
//   [0, nb_hrel)          hrel16[n][r*32+o] = fp16( sum_i h[n][i]*rel_w[r][i][o] )
//   [nb_hrel, +NPLACE)    place: LDS cursors = histT(bin-local) + binTot(bin base);
//                         each (block,bin) writes a contiguous run. LDS atomics only.
// ---------------------------------------------------------------------------
__global__ __launch_bounds__(256) void k_fused2(
        const float* __restrict__ h, const float* __restrict__ rel_w,
        __half* __restrict__ hrel16,
        const int* __restrict__ src, const int* __restrict__ dst,
        const int* __restrict__ et,
        const int* __restrict__ histT, const int* __restrict__ binTot,
        int* __restrict__ tmp,
        int N, int E, int nb_hrel) {
    __shared__ float hbuf[32 * 33];
    __shared__ int cur[256];
    int bx = blockIdx.x;
    int t = threadIdx.x;
    if (bx < nb_hrel) {
        // ---- hrel (fp16 out) ----
        int n0 = bx * 32;
        #pragma unroll
        for (int k = 0; k < 4; ++k) {
            int idx = t + 256 * k;
            int row = idx >> 5, col = idx & 31;
            int n = n0 + row;
            hbuf[row * 33 + col] = (n < N) ? h[n * 32 + col] : 0.f;
        }
        __syncthreads();
        int w = t >> 6;
        int lane = t & 63;
        const float4* Wg = (const float4*)rel_w;
        int base_f4 = (lane >> 3) * 256 + (lane & 7);
        float4 a0[8], a1[8];
        #pragma unroll
        for (int j = 0; j < 8; ++j) {
            a0[j] = make_float4(0.f, 0.f, 0.f, 0.f);
            a1[j] = make_float4(0.f, 0.f, 0.f, 0.f);
        }
        int brow = w * 8;
        #pragma unroll 4
        for (int i = 0; i < 32; ++i) {
            float4 w0 = Wg[base_f4 + i * 8];
            float4 w1 = Wg[base_f4 + i * 8 + 2048];
            #pragma unroll
            for (int j = 0; j < 8; ++j) {
                float hv = hbuf[(brow + j) * 33 + i];
                a0[j].x += hv * w0.x; a0[j].y += hv * w0.y; a0[j].z += hv * w0.z; a0[j].w += hv * w0.w;
                a1[j].x += hv * w1.x; a1[j].y += hv * w1.y; a1[j].z += hv * w1.z; a1[j].w += hv * w1.w;
            }
        }
        #pragma unroll
        for (int j = 0; j < 8; ++j) {
            int n = n0 + brow + j;
            if (n < N) {
                size_t b0 = (size_t)n * 512 + lane * 4;
                *(__half2*)&hrel16[b0]       = __floats2half2_rn(a0[j].x, a0[j].y);
                *(__half2*)&hrel16[b0 + 2]   = __floats2half2_rn(a0[j].z, a0[j].w);
                *(__half2*)&hrel16[b0 + 256] = __floats2half2_rn(a1[j].x, a1[j].y);
                *(__half2*)&hrel16[b0 + 258] = __floats2half2_rn(a1[j].z, a1[j].w);
            }
        }
    } else {
        // ---- place ----
        int nsb = (N + NPB - 1) / NPB;
        int blk = bx - nb_hrel;
        if (t < nsb) cur[t] = histT[t * NPLACE + blk] + binTot[t];
        __syncthreads();
        int bpb = (E + NPLACE - 1) / NPLACE;
        int e0 = blk * bpb;
        int e1 = e0 + bpb; if (e1 > E) e1 = E;
        for (int e = e0 + t; e < e1; e += 256) {
            int d = dst[e];
            int pos = atomicAdd(&cur[d >> 9], 1);    // absolute position
            tmp[pos] = src[e] | (et[e] << 17) | ((d & 511) << 21);
        }
    }
}

// ---------------------------------------------------------------------------
// k_sortbin: one block per super-bin. Counts per-node degrees in LDS,
// block-scans them -> writes rowptr[n] (global CSR) + scale_s partial,
// then places records in exact per-node order. No global atomics except
// one scale_s add per block.
// ---------------------------------------------------------------------------
__global__ __launch_bounds__(256) void k_sortbin(
        const int* __restrict__ tmp, int* __restrict__ packed,
        const int* __restrict__ binTot,
        int* __restrict__ rowptr, float* __restrict__ scale_s,
        int N, int E) {
    __shared__ int cnt[NPB];
    __shared__ int sa[256];
    __shared__ float sf[256];
    int t = threadIdx.x;
    int bin = blockIdx.x;
    int n0 = bin * NPB;
    cnt[t] = 0; cnt[t + 256] = 0;
    __syncthreads();
    int start = binTot[bin], end = binTot[bin + 1];
    // pass 1: count per-node degrees
    for (int i = start + t; i < end; i += 256)
        atomicAdd(&cnt[(tmp[i] >> 21) & 511], 1);
    __syncthreads();
    int c0 = cnt[2 * t], c1 = cnt[2 * t + 1];
    sa[t] = c0 + c1;
    __syncthreads();
    for (int off = 1; off < 256; off <<= 1) {
        int x = (t >= off) ? sa[t - off] : 0;
        __syncthreads();
        sa[t] += x;
        __syncthreads();
    }
    int excl0 = sa[t] - (c0 + c1);                 // exclusive prefix at 2t
    int excl1 = excl0 + c0;
    int nA = n0 + 2 * t, nB = n0 + 2 * t + 1;
    if (nA <= N) rowptr[nA] = start + excl0;
    if (nB <= N) rowptr[nB] = start + excl1;
    // scale partial
    float f = 0.f;
    if (nA < N) f += logf((float)c0 + 1.f);
    if (nB < N) f += logf((float)c1 + 1.f);
    sf[t] = f;
    __syncthreads();
    for (int s2 = 128; s2 > 0; s2 >>= 1) {
        if (t < s2) sf[t] += sf[t + s2];
        __syncthreads();
    }
    if (t == 0) atomicAdd(scale_s, sf[0]);
    // seed cursors (reuse cnt)
    cnt[2 * t] = start + excl0;
    cnt[2 * t + 1] = start + excl1;
    __syncthreads();
    // pass 2: place
    for (int i = start + t; i < end; i += 256) {
        int rec = tmp[i];
        int dl = (rec >> 21) & 511;
        int pos = atomicAdd(&cnt[dl], 1);
        packed[pos] = rec;
    }
}

// ---------------------------------------------------------------------------
// k_node_agg: one node per 64-lane wave, 2 edges per step (one per 32-half),
// 2 steps batched (4 edges' gathers in flight). CSR gather from fp16 tables,
// DPP attention reduce, register accumulate, fused epilogue.
// ---------------------------------------------------------------------------
__global__ __launch_bounds__(256) void k_node_agg(
        const __half* __restrict__ hrel16, const __half* __restrict__ hA1,
        const float* __restrict__ hA2, const float* __restrict__ relA,
        const float* __restrict__ B_w, const float* __restrict__ B_b,
        const float* __restrict__ curr, const float* __restrict__ bias,
        const int* __restrict__ rowptr,
        const int* __restrict__ packed, const float* __restrict__ scale_s,
        float* __restrict__ out, int N) {
    int t = threadIdx.x;
    int wave = t >> 6, t64 = t & 63;
    int half = t64 >> 5, o = t64 & 31;
    int n = blockIdx.x * 4 + wave;
    if (n >= N) return;
    int r0 = rowptr[n], r1 = rowptr[n + 1];
    float hA2n = hA2[n * 32 + o];
    float bwo = B_w[o];
    float bb  = B_b[0];
    float acc = 0.f;
    for (int c0 = r0; c0 < r1; c0 += 64) {
        int j = c0 + t64;
        int pk = (j < r1) ? packed[j] : 0;
        int m = r1 - c0; if (m > 64) m = 64;
        for (int k = 0; k < m; k += 4) {
            int idxA = k + half;
            int idxB = k + 2 + half;
            int pkA = __shfl(pk, idxA, 64);
            int pkB = __shfl(pk, idxB, 64);
            int sA = pkA & 0x1FFFF, rA = (pkA >> 17) & 15;
            int sB = pkB & 0x1FFFF, rB = (pkB >> 17) & 15;
            // issue all four gathers before any math
            float msgA = __half2float(hrel16[(size_t)sA * 512 + (rA << 5) + o]);
            float a1A  = __half2float(hA1[(sA << 5) + o]);
            float msgB = __half2float(hrel16[(size_t)sB * 512 + (rB << 5) + o]);
            float a1B  = __half2float(hA1[(sB << 5) + o]);
            float zA = a1A + hA2n + relA[(rA << 5) + o];
            float zB = a1B + hA2n + relA[(rB << 5) + o];
            float pA = fmaxf(zA, 0.f) * bwo;
            float pB = fmaxf(zB, 0.f) * bwo;
            pA = dpp_add_f<0x111>(pA); pB = dpp_add_f<0x111>(pB);
            pA = dpp_add_f<0x112>(pA); pB = dpp_add_f<0x112>(pB);
            pA = dpp_add_f<0x114>(pA); pB = dpp_add_f<0x114>(pB);
            pA = dpp_add_f<0x118>(pA); pB = dpp_add_f<0x118>(pB);
            pA = dpp_add_f<0x142>(pA); pB = dpp_add_f<0x142>(pB);
            pA = __shfl(pA, 31, 32) + bb;
            pB = __shfl(pB, 31, 32) + bb;
            float aA = 1.f / (1.f + __expf(-pA));
            float aB = 1.f / (1.f + __expf(-pB));
            acc += (idxA < m) ? aA * msgA : 0.f;
            acc += (idxB < m) ? aB * msgB : 0.f;
        }
    }
    acc += __shfl_xor(acc, 32, 64);
    if (half == 0) {
        float deg = (float)(r1 - r0);
        float smean = scale_s[0] / (float)N;
        float scale = logf(deg + 1.0f);
        float v = curr[n * 32 + o] + (scale / smean) * acc / fmaxf(deg, 1.f) + bias[o];
        out[n * 32 + o] = fmaxf(v, 0.f);
    }
}

extern "C" void kernel_launch(void* const* d_in, const int* in_sizes, int n_in,
                              void* d_out, int out_size, void* d_ws, size_t ws_size,
                              hipStream_t stream) {
    const float* h        = (const float*)d_in[0];
    const float* weight   = (const float*)d_in[1];
    const float* w_comp   = (const float*)d_in[2];
    const float* slw      = (const float*)d_in[3];
    const float* bias     = (const float*)d_in[4];
    const float* attn_emb = (const float*)d_in[5];
    const float* A_w      = (const float*)d_in[6];
    const float* A_b      = (const float*)d_in[7];
    const float* B_w      = (const float*)d_in[8];
    const float* B_b      = (const float*)d_in[9];
    const int*   src      = (const int*)d_in[10];
    const int*   dst      = (const int*)d_in[11];
    const int*   et       = (const int*)d_in[12];
    float*       out      = (float*)d_out;

    int N = in_sizes[0] / 32;
    int E = in_sizes[10];
    int nsb = (N + NPB - 1) / NPB;                 // super-bins

    char* ws = (char*)d_ws;
    size_t off = 0;
    auto alloc = [&](size_t nbytes) {
        char* p = ws + off;
        off += (nbytes + 63) & ~((size_t)63);
        return p;
    };
    float*  scale_s = (float*) alloc(4);
    size_t zero_bytes = off;                       // scale_s only
    int*    rowptr  = (int*)   alloc((size_t)(N + 1) * 4);
    int*    histT   = (int*)   alloc((size_t)nsb * NPLACE * 4);
    int*    binTot  = (int*)   alloc((size_t)(nsb + 1) * 4);
    float*  rel_w   = (float*) alloc((size_t)NREL * 1024 * 4);
    float*  relA    = (float*) alloc((size_t)NREL * 32 * 4);
    __half* hA1     = (__half*)alloc((size_t)N * 32 * 2);
    float*  hA2     = (float*) alloc((size_t)N * 32 * 4);
    float*  curr    = (float*) alloc((size_t)N * 32 * 4);
    int*    tmp     = (int*)   alloc((size_t)E * 4);
    int*    packed  = (int*)   alloc((size_t)E * 4);
    __half* hrel16  = (__half*)alloc((size_t)N * 512 * 2);
    size_t need = off;

    if (ws_size < need) {
        fprintf(stderr, "kernel_launch: ws too small (%zu < %zu bytes) — no work launched\n",
                ws_size, need);
        return;
    }

    (void)hipMemsetAsync(d_ws, 0, zero_bytes, stream);

    int nb_pre = (N + 31) / 32;
    k_fused1<<<nb_pre + 64 + NPLACE, 256, 0, stream>>>(
        h, A_w, slw, weight, w_comp, attn_emb, A_b, dst,
        hA1, hA2, curr, rel_w, relA, histT, N, E, nb_pre);

    k_scanH<<<nsb, NPLACE, 0, stream>>>(histT, binTot);
    k_scanB<<<1, 1024, 0, stream>>>(binTot, nsb);

    int nb_hrel = (N + 31) / 32;
    k_fused2<<<nb_hrel + NPLACE, 256, 0, stream>>>(
        h, rel_w, hrel16, src, dst, et, histT, binTot, tmp, N, E, nb_hrel);

    k_sortbin<<<nsb, 256, 0, stream>>>(tmp, packed, binTot, rowptr, scale_s, N, E);

    k_node_agg<<<(N + 3) / 4, 256, 0, stream>>>(
        hrel16, hA1, hA2, relA, B_w, B_b, curr, bias,
        rowptr, packed, scale_s, out, N);
}